// Round 5
// baseline (463.207 us; speedup 1.0000x reference)
//
#include <hip/hip_runtime.h>

#define COLS    32768
#define LOG2C   15
#define KSEL    32
#define GCAP    512       // global per-row candidate cap (expected ~203 at BAR=2.5, 21 sigma)
#define CAP     1024      // LDS candidate buffer (fallback radix path)
#define REF_CAP 256
#define NT      256
#define BAR     2.5f
#define BLOCKS1 2048      // grid-stride streaming kernel: 8 blocks/CU, one dense sweep

typedef float f32x4 __attribute__((ext_vector_type(4)));

// key = (float_bits << 32) | (0xFFFF - idx_in_row)
// positive float bits are monotonic in value; low 16 bits break ties so that
// larger key == (larger value, or equal value with smaller index) — matching
// jax.lax.top_k tie order. All keys distinct since idx distinct.
__device__ __forceinline__ unsigned long long mk_key(float v, int idx) {
    return ((unsigned long long)__float_as_uint(v) << 32) | (unsigned)(0xFFFF - idx);
}

// ---- K1: single dense grid-stride sweep. Read x, write zeros, push rare
// candidates (0.6%/lane) to per-row global buffers. DRAM-friendly: the whole
// grid advances one contiguous ~8MB window at a time (copy-ubench pattern),
// instead of 2048 independent per-row streams. ----
__global__ __launch_bounds__(NT) void stream_zero_collect(
        const float* __restrict__ x, float* __restrict__ out,
        int* __restrict__ cnt, unsigned long long* __restrict__ gcand, int nv4) {
    const f32x4* __restrict__ x4 = (const f32x4*)x;
    f32x4* __restrict__ o4 = (f32x4*)out;
    const int stride = gridDim.x * NT;
#pragma unroll 4
    for (int g = blockIdx.x * NT + threadIdx.x; g < nv4; g += stride) {
        const f32x4 v = __builtin_nontemporal_load(x4 + g);
        f32x4 z = 0;
        o4[g] = z;
        const float m = fmaxf(fmaxf(v.x, v.y), fmaxf(v.z, v.w));
        if (m > BAR) {                      // rare: ~21% of wave-iters, ~1.6 lanes
            const int row = g >> (LOG2C - 2);        // 4 elems never straddle a row
            const int bi = (g << 2) & (COLS - 1);
            const int nb = (v.x > BAR) + (v.y > BAR) + (v.z > BAR) + (v.w > BAR);
            int p = atomicAdd(&cnt[row], nb);        // device-scope, L2 atomic
            unsigned long long* __restrict__ gr = gcand + (size_t)row * GCAP;
            if (v.x > BAR) { if (p < GCAP) gr[p] = mk_key(v.x, bi + 0); ++p; }
            if (v.y > BAR) { if (p < GCAP) gr[p] = mk_key(v.y, bi + 1); ++p; }
            if (v.z > BAR) { if (p < GCAP) gr[p] = mk_key(v.z, bi + 2); ++p; }
            if (v.w > BAR) { if (p < GCAP) gr[p] = mk_key(v.w, bi + 3); ++p; }
        }
    }
}

// ---- K2: per-row select + scatter from the global candidate buffers. ----
__global__ __launch_bounds__(NT) void select_scatter(
        const float* __restrict__ x, float* __restrict__ out,
        const int* __restrict__ cnt, const unsigned long long* __restrict__ gcand) {
    __shared__ unsigned long long cand[CAP];
    __shared__ unsigned long long refbuf[REF_CAP];
    __shared__ unsigned hist[256];
    __shared__ int s_cnt, s_bstar, s_rcnt, s_cum;

    const int tid = threadIdx.x;
    const size_t row = blockIdx.x;
    const float* __restrict__ xr = x + row * COLS;
    float* __restrict__ outr = out + row * COLS;
    const int N = cnt[row];

    if (N >= KSEL && N <= GCAP) {
        // ---- common path: stage candidates to LDS, histogram-prune, rank-select ----
        const unsigned long long* __restrict__ gr = gcand + row * GCAP;
        for (int c = tid; c < N; c += NT) cand[c] = gr[c];
        hist[tid] = 0;
        if (tid == 0) s_rcnt = 0;
        __syncthreads();
        for (int c = tid; c < N; c += NT) {
            unsigned bits = (unsigned)(cand[c] >> 32);
            unsigned b16 = (bits >> 16) - 0x4000u;   // bits >= 0x40200000 since v > 2.5
            if (b16 > 255u) b16 = 255u;              // saturate (keeps monotonicity)
            atomicAdd(&hist[b16], 1u);
        }
        __syncthreads();
        // single-wave barrier-free suffix scan: lane owns bins [4l, 4l+3]
        if (tid < 64) {
            const int lane = tid;
            const unsigned h0 = hist[4 * lane + 0], h1 = hist[4 * lane + 1];
            const unsigned h2 = hist[4 * lane + 2], h3 = hist[4 * lane + 3];
            const unsigned s3 = h3, s2 = h2 + s3, s1 = h1 + s2, s0 = h0 + s1;
            unsigned acc = s0;
#pragma unroll
            for (int off = 1; off < 64; off <<= 1) {
                unsigned o = __shfl_down(acc, off, 64);
                if (lane + off < 64) acc += o;
            }
            const unsigned above = acc - s0;        // sum over lanes > lane
            const unsigned suf0 = above + s0, suf1 = above + s1;
            const unsigned suf2 = above + s2, suf3 = above + s3;
            unsigned nxt = __shfl_down(suf0, 1, 64);
            const unsigned suf4 = (lane == 63) ? 0u : nxt;
            if (suf0 >= KSEL && suf1 < KSEL) s_bstar = 4 * lane + 0;
            if (suf1 >= KSEL && suf2 < KSEL) s_bstar = 4 * lane + 1;
            if (suf2 >= KSEL && suf3 < KSEL) s_bstar = 4 * lane + 2;
            if (suf3 >= KSEL && suf4 < KSEL) s_bstar = 4 * lane + 3;
        }
        __syncthreads();
        const int bstar = s_bstar;
        for (int c = tid; c < N; c += NT) {
            const unsigned long long kc = cand[c];
            unsigned bits = (unsigned)(kc >> 32);
            unsigned b16 = (bits >> 16) - 0x4000u;
            if (b16 > 255u) b16 = 255u;
            if ((int)b16 >= bstar) { int p = atomicAdd(&s_rcnt, 1); if (p < REF_CAP) refbuf[p] = kc; }
        }
        __syncthreads();
        const int M = s_rcnt;
        if (M <= REF_CAP) {
            for (int c = tid; c < M; c += NT) {
                const unsigned long long kc = refbuf[c];
                int rank = 0;
                for (int j = 0; j < M; ++j) rank += (refbuf[j] > kc) ? 1 : 0;
                if (rank < KSEL)
                    outr[0xFFFF - (int)(kc & 0xFFFFu)] = __uint_as_float((unsigned)(kc >> 32));
            }
        } else {
            // refine overflow (mass ties) — exact rank over full candidate list
            for (int c = tid; c < N; c += NT) {
                const unsigned long long kc = cand[c];
                int rank = 0;
                for (int j = 0; j < N; ++j) rank += (cand[j] > kc) ? 1 : 0;
                if (rank < KSEL)
                    outr[0xFFFF - (int)(kc & 0xFFFFu)] = __uint_as_float((unsigned)(kc >> 32));
            }
        }
        return;
    }

    // ---- exact fallback (N < K or buffer overflow; never on N(0,1)): radix
    // select on the row itself, ignoring gcand. out row is already zeroed. ----
    unsigned pref = 0, thr = 1;
    int need = KSEL, above = 0;
    for (int s = 24; s >= 0; s -= 8) {
        __syncthreads();
        hist[tid] = 0;
        __syncthreads();
        for (int i = tid; i < COLS; i += NT) {
            float v = xr[i];
            if (v > 0.f) {
                unsigned bits = __float_as_uint(v);
                if (s == 24 || (bits >> (s + 8)) == pref)
                    atomicAdd(&hist[(bits >> s) & 255u], 1u);
            }
        }
        __syncthreads();
        if (tid == 0) {
            int cum = 0, b = 255;
            for (; b >= 0; --b) { if (cum + (int)hist[b] >= need) break; cum += (int)hist[b]; }
            s_bstar = b; s_cum = cum;
        }
        __syncthreads();
        const int b = s_bstar, cum = s_cum;
        if (b < 0) { thr = 1; break; }    // fewer than K positives: take all positives
        above += cum;
        need -= cum;
        pref = (pref << 8) | (unsigned)b;
        thr = pref << s;
        const int total = above + (int)hist[b];
        if (total <= CAP || s == 0) break;
    }
    __syncthreads();
    if (tid == 0) s_cnt = 0;
    __syncthreads();
    for (int i = tid; i < COLS; i += NT) {
        float v = xr[i];
        if (v > 0.f) {
            unsigned bits = __float_as_uint(v);
            if (bits >= thr) {
                int p = atomicAdd(&s_cnt, 1);
                if (p < CAP) cand[p] = ((unsigned long long)bits << 32) | (unsigned)(0xFFFF - i);
            }
        }
    }
    __syncthreads();
    const int M2 = min(s_cnt, CAP);
    for (int c = tid; c < M2; c += NT) {
        const unsigned long long kc = cand[c];
        int rank = 0;
        for (int j = 0; j < M2; ++j) rank += (cand[j] > kc) ? 1 : 0;
        if (rank < KSEL)
            outr[0xFFFF - (int)(kc & 0xFFFFu)] = __uint_as_float((unsigned)(kc >> 32));
    }
}

// ---- fused single-kernel fallback (used only if ws_size is too small) ----
__global__ __launch_bounds__(NT) void topk_fused_kernel(const float* __restrict__ x,
                                                        float* __restrict__ out) {
    __shared__ unsigned long long cand[CAP];
    __shared__ unsigned long long refbuf[REF_CAP];
    __shared__ unsigned hist[256];
    __shared__ int s_cnt, s_bstar, s_rcnt, s_cum;

    const int tid = threadIdx.x;
    const size_t row = blockIdx.x;
    const float* __restrict__ xr = x + row * COLS;
    float* __restrict__ outr = out + row * COLS;

    if (tid == 0) { s_cnt = 0; s_rcnt = 0; }
    __syncthreads();

    const f32x4* __restrict__ xr4 = (const f32x4*)xr;
    f32x4* __restrict__ our4 = (f32x4*)outr;
#pragma unroll 4
    for (int i = 0; i < COLS / 4 / NT; ++i) {
        const int e = i * NT + tid;
        f32x4 v = __builtin_nontemporal_load(xr4 + e);
        f32x4 z = 0;
        __builtin_nontemporal_store(z, our4 + e);
        const float m = fmaxf(fmaxf(v.x, v.y), fmaxf(v.z, v.w));
        if (m > BAR) {
            const int bi = e * 4;
            if (v.x > BAR) { int p = atomicAdd(&s_cnt, 1); if (p < CAP) cand[p] = mk_key(v.x, bi + 0); }
            if (v.y > BAR) { int p = atomicAdd(&s_cnt, 1); if (p < CAP) cand[p] = mk_key(v.y, bi + 1); }
            if (v.z > BAR) { int p = atomicAdd(&s_cnt, 1); if (p < CAP) cand[p] = mk_key(v.z, bi + 2); }
            if (v.w > BAR) { int p = atomicAdd(&s_cnt, 1); if (p < CAP) cand[p] = mk_key(v.w, bi + 3); }
        }
    }
    __syncthreads();
    const int N = s_cnt;

    if (N >= KSEL && N <= CAP) {
        hist[tid] = 0;
        __syncthreads();
        for (int c = tid; c < N; c += NT) {
            unsigned bits = (unsigned)(cand[c] >> 32);
            unsigned b16 = (bits >> 16) - 0x4000u;
            if (b16 > 255u) b16 = 255u;
            atomicAdd(&hist[b16], 1u);
        }
        __syncthreads();
        if (tid < 64) {
            const int lane = tid;
            const unsigned h0 = hist[4 * lane + 0], h1 = hist[4 * lane + 1];
            const unsigned h2 = hist[4 * lane + 2], h3 = hist[4 * lane + 3];
            const unsigned s3 = h3, s2 = h2 + s3, s1 = h1 + s2, s0 = h0 + s1;
            unsigned acc = s0;
#pragma unroll
            for (int off = 1; off < 64; off <<= 1) {
                unsigned o = __shfl_down(acc, off, 64);
                if (lane + off < 64) acc += o;
            }
            const unsigned above = acc - s0;
            const unsigned suf0 = above + s0, suf1 = above + s1;
            const unsigned suf2 = above + s2, suf3 = above + s3;
            unsigned nxt = __shfl_down(suf0, 1, 64);
            const unsigned suf4 = (lane == 63) ? 0u : nxt;
            if (suf0 >= KSEL && suf1 < KSEL) s_bstar = 4 * lane + 0;
            if (suf1 >= KSEL && suf2 < KSEL) s_bstar = 4 * lane + 1;
            if (suf2 >= KSEL && suf3 < KSEL) s_bstar = 4 * lane + 2;
            if (suf3 >= KSEL && suf4 < KSEL) s_bstar = 4 * lane + 3;
        }
        __syncthreads();
        const int bstar = s_bstar;
        for (int c = tid; c < N; c += NT) {
            const unsigned long long kc = cand[c];
            unsigned bits = (unsigned)(kc >> 32);
            unsigned b16 = (bits >> 16) - 0x4000u;
            if (b16 > 255u) b16 = 255u;
            if ((int)b16 >= bstar) { int p = atomicAdd(&s_rcnt, 1); if (p < REF_CAP) refbuf[p] = kc; }
        }
        __syncthreads();
        const int M = s_rcnt;
        if (M <= REF_CAP) {
            for (int c = tid; c < M; c += NT) {
                const unsigned long long kc = refbuf[c];
                int rank = 0;
                for (int j = 0; j < M; ++j) rank += (refbuf[j] > kc) ? 1 : 0;
                if (rank < KSEL)
                    outr[0xFFFF - (int)(kc & 0xFFFFu)] = __uint_as_float((unsigned)(kc >> 32));
            }
        } else {
            for (int c = tid; c < N; c += NT) {
                const unsigned long long kc = cand[c];
                int rank = 0;
                for (int j = 0; j < N; ++j) rank += (cand[j] > kc) ? 1 : 0;
                if (rank < KSEL)
                    outr[0xFFFF - (int)(kc & 0xFFFFu)] = __uint_as_float((unsigned)(kc >> 32));
            }
        }
        return;
    }

    unsigned pref = 0, thr = 1;
    int need = KSEL, above = 0;
    for (int s = 24; s >= 0; s -= 8) {
        __syncthreads();
        hist[tid] = 0;
        __syncthreads();
        for (int i = tid; i < COLS; i += NT) {
            float v = xr[i];
            if (v > 0.f) {
                unsigned bits = __float_as_uint(v);
                if (s == 24 || (bits >> (s + 8)) == pref)
                    atomicAdd(&hist[(bits >> s) & 255u], 1u);
            }
        }
        __syncthreads();
        if (tid == 0) {
            int cum = 0, b = 255;
            for (; b >= 0; --b) { if (cum + (int)hist[b] >= need) break; cum += (int)hist[b]; }
            s_bstar = b; s_cum = cum;
        }
        __syncthreads();
        const int b = s_bstar, cum = s_cum;
        if (b < 0) { thr = 1; break; }
        above += cum;
        need -= cum;
        pref = (pref << 8) | (unsigned)b;
        thr = pref << s;
        const int total = above + (int)hist[b];
        if (total <= CAP || s == 0) break;
    }
    __syncthreads();
    if (tid == 0) s_cnt = 0;
    __syncthreads();
    for (int i = tid; i < COLS; i += NT) {
        float v = xr[i];
        if (v > 0.f) {
            unsigned bits = __float_as_uint(v);
            if (bits >= thr) {
                int p = atomicAdd(&s_cnt, 1);
                if (p < CAP) cand[p] = ((unsigned long long)bits << 32) | (unsigned)(0xFFFF - i);
            }
        }
    }
    __syncthreads();
    const int M2 = min(s_cnt, CAP);
    for (int c = tid; c < M2; c += NT) {
        const unsigned long long kc = cand[c];
        int rank = 0;
        for (int j = 0; j < M2; ++j) rank += (cand[j] > kc) ? 1 : 0;
        if (rank < KSEL)
            outr[0xFFFF - (int)(kc & 0xFFFFu)] = __uint_as_float((unsigned)(kc >> 32));
    }
}

extern "C" void kernel_launch(void* const* d_in, const int* in_sizes, int n_in,
                              void* d_out, int out_size, void* d_ws, size_t ws_size,
                              hipStream_t stream) {
    const float* x = (const float*)d_in[0];
    float* out = (float*)d_out;
    const int rows = in_sizes[0] / COLS;
    const int nv4 = in_sizes[0] / 4;
    const size_t cnt_bytes = (size_t)rows * sizeof(int);
    const size_t need = cnt_bytes + (size_t)rows * GCAP * sizeof(unsigned long long);

    if (ws_size >= need) {
        int* cnt = (int*)d_ws;
        unsigned long long* gcand = (unsigned long long*)((char*)d_ws + cnt_bytes);
        hipMemsetAsync(cnt, 0, cnt_bytes, stream);                       // 16 KB
        hipLaunchKernelGGL(stream_zero_collect, dim3(BLOCKS1), dim3(NT), 0, stream,
                           x, out, cnt, gcand, nv4);
        hipLaunchKernelGGL(select_scatter, dim3(rows), dim3(NT), 0, stream,
                           x, out, cnt, gcand);
    } else {
        hipLaunchKernelGGL(topk_fused_kernel, dim3(rows), dim3(NT), 0, stream, x, out);
    }
}

// Round 6
// 238.323 us; speedup vs baseline: 1.9436x; 1.9436x over previous
//
#include <hip/hip_runtime.h>

#define COLS    32768
#define KSEL    32
#define GCAP    512       // per-row LDS candidate cap (expected ~203 at BAR=2.5, 21 sigma)
#define REF_CAP 256       // refined buffer after histogram prune (expected ~34)
#define NTHR    1024      // fat block: 16 waves
#define GRID    512       // 2 blocks/CU resident -> 512 concurrent DRAM streams (vs 2048)
#define BAR     2.5f

typedef float f32x4 __attribute__((ext_vector_type(4)));

// key = (float_bits << 32) | (0xFFFF - idx_in_row)
// positive float bits are monotonic in value; low 16 bits break ties so that
// larger key == (larger value, or equal value with smaller index) — matching
// jax.lax.top_k tie order. All keys distinct since idx distinct.
__device__ __forceinline__ unsigned long long mk_key(float v, int idx) {
    return ((unsigned long long)__float_as_uint(v) << 32) | (unsigned)(0xFFFF - idx);
}

// One fat block processes ROWS_PER consecutive rows (contiguous 1MB region):
// fewer, longer DRAM streams. All candidate aggregation stays in LDS.
__global__ __launch_bounds__(NTHR, 8) void topk_fat_kernel(const float* __restrict__ x,
                                                           float* __restrict__ out, int rows) {
    __shared__ unsigned long long cand[GCAP];
    __shared__ unsigned long long refbuf[REF_CAP];
    __shared__ unsigned hist[256];
    __shared__ int s_cnt, s_bstar, s_rcnt, s_cum;

    const int tid = threadIdx.x;
    const int rows_per = (rows + (int)gridDim.x - 1) / (int)gridDim.x;
    const int r0 = (int)blockIdx.x * rows_per;

    for (int rr = 0; rr < rows_per; ++rr) {
        const int row = r0 + rr;
        if (row >= rows) break;
        const float* __restrict__ xr = x + (size_t)row * COLS;
        float* __restrict__ outr = out + (size_t)row * COLS;
        const f32x4* __restrict__ xr4 = (const f32x4*)xr;
        f32x4* __restrict__ our4 = (f32x4*)outr;

        if (tid == 0) { s_cnt = 0; s_rcnt = 0; }
        if (tid < 256) hist[tid] = 0;
        __syncthreads();                                   // B1

        // ---- stream this row: NT load, NT store zeros, rare LDS push ----
#pragma unroll
        for (int i = 0; i < COLS / 4 / NTHR; ++i) {        // 8 iterations
            const int e = i * NTHR + tid;
            const f32x4 v = __builtin_nontemporal_load(xr4 + e);
            f32x4 z = 0;
            __builtin_nontemporal_store(z, our4 + e);
            const float m = fmaxf(fmaxf(v.x, v.y), fmaxf(v.z, v.w));
            if (m > BAR) {                                 // ~0.6% of lanes
                const int bi = e * 4;
                if (v.x > BAR) { int p = atomicAdd(&s_cnt, 1); if (p < GCAP) cand[p] = mk_key(v.x, bi + 0); }
                if (v.y > BAR) { int p = atomicAdd(&s_cnt, 1); if (p < GCAP) cand[p] = mk_key(v.y, bi + 1); }
                if (v.z > BAR) { int p = atomicAdd(&s_cnt, 1); if (p < GCAP) cand[p] = mk_key(v.z, bi + 2); }
                if (v.w > BAR) { int p = atomicAdd(&s_cnt, 1); if (p < GCAP) cand[p] = mk_key(v.w, bi + 3); }
            }
        }
        __syncthreads();                                   // B2
        const int N = s_cnt;

        if (N >= KSEL && N <= GCAP) {
            // ---- histogram-prune candidates, then rank-select top-K ----
            for (int c = tid; c < N; c += NTHR) {
                unsigned bits = (unsigned)(cand[c] >> 32);
                unsigned b16 = (bits >> 16) - 0x4000u;     // bits >= 0x40200000 since v > 2.5
                if (b16 > 255u) b16 = 255u;                // saturate (keeps monotonicity)
                atomicAdd(&hist[b16], 1u);
            }
            __syncthreads();                               // B3
            // single-wave barrier-free suffix scan: lane owns bins [4l, 4l+3]
            if (tid < 64) {
                const int lane = tid;
                const unsigned h0 = hist[4 * lane + 0], h1 = hist[4 * lane + 1];
                const unsigned h2 = hist[4 * lane + 2], h3 = hist[4 * lane + 3];
                const unsigned s3 = h3, s2 = h2 + s3, s1 = h1 + s2, s0 = h0 + s1;
                unsigned acc = s0;
#pragma unroll
                for (int off = 1; off < 64; off <<= 1) {
                    unsigned o = __shfl_down(acc, off, 64);
                    if (lane + off < 64) acc += o;
                }
                const unsigned above = acc - s0;           // sum over lanes > lane
                const unsigned suf0 = above + s0, suf1 = above + s1;
                const unsigned suf2 = above + s2, suf3 = above + s3;
                unsigned nxt = __shfl_down(suf0, 1, 64);
                const unsigned suf4 = (lane == 63) ? 0u : nxt;
                if (suf0 >= KSEL && suf1 < KSEL) s_bstar = 4 * lane + 0;
                if (suf1 >= KSEL && suf2 < KSEL) s_bstar = 4 * lane + 1;
                if (suf2 >= KSEL && suf3 < KSEL) s_bstar = 4 * lane + 2;
                if (suf3 >= KSEL && suf4 < KSEL) s_bstar = 4 * lane + 3;
            }
            __syncthreads();                               // B4
            const int bstar = s_bstar;
            for (int c = tid; c < N; c += NTHR) {
                const unsigned long long kc = cand[c];
                unsigned bits = (unsigned)(kc >> 32);
                unsigned b16 = (bits >> 16) - 0x4000u;
                if (b16 > 255u) b16 = 255u;
                if ((int)b16 >= bstar) { int p = atomicAdd(&s_rcnt, 1); if (p < REF_CAP) refbuf[p] = kc; }
            }
            __syncthreads();                               // B5
            const int M = s_rcnt;
            if (M <= REF_CAP) {
                for (int c = tid; c < M; c += NTHR) {
                    const unsigned long long kc = refbuf[c];
                    int rank = 0;
                    for (int j = 0; j < M; ++j) rank += (refbuf[j] > kc) ? 1 : 0;
                    if (rank < KSEL)
                        outr[0xFFFF - (int)(kc & 0xFFFFu)] = __uint_as_float((unsigned)(kc >> 32));
                }
            } else {
                // refine overflow (mass ties) — exact rank over full candidate list
                for (int c = tid; c < N; c += NTHR) {
                    const unsigned long long kc = cand[c];
                    int rank = 0;
                    for (int j = 0; j < N; ++j) rank += (cand[j] > kc) ? 1 : 0;
                    if (rank < KSEL)
                        outr[0xFFFF - (int)(kc & 0xFFFFu)] = __uint_as_float((unsigned)(kc >> 32));
                }
            }
            __syncthreads();                               // B6: cand/s_* safe for next row
            continue;
        }

        // ---- exact fallback (N < K or overflow; never on N(0,1)): radix select
        // re-reading the row. Out row already zeroed above. ----
        unsigned pref = 0, thr = 1;
        int need = KSEL, above = 0;
        for (int s = 24; s >= 0; s -= 8) {
            __syncthreads();
            if (tid < 256) hist[tid] = 0;
            __syncthreads();
            for (int i = tid; i < COLS; i += NTHR) {
                float v = xr[i];
                if (v > 0.f) {
                    unsigned bits = __float_as_uint(v);
                    if (s == 24 || (bits >> (s + 8)) == pref)
                        atomicAdd(&hist[(bits >> s) & 255u], 1u);
                }
            }
            __syncthreads();
            if (tid == 0) {
                int cum = 0, b = 255;
                for (; b >= 0; --b) { if (cum + (int)hist[b] >= need) break; cum += (int)hist[b]; }
                s_bstar = b; s_cum = cum;
            }
            __syncthreads();
            const int b = s_bstar, cum = s_cum;
            if (b < 0) { thr = 1; break; }   // fewer than K positives: take all positives
            above += cum;
            need -= cum;
            pref = (pref << 8) | (unsigned)b;
            thr = pref << s;
            const int total = above + (int)hist[b];
            if (total <= GCAP || s == 0) break;
        }
        __syncthreads();
        if (tid == 0) s_cnt = 0;
        __syncthreads();
        for (int i = tid; i < COLS; i += NTHR) {
            float v = xr[i];
            if (v > 0.f) {
                unsigned bits = __float_as_uint(v);
                if (bits >= thr) {
                    int p = atomicAdd(&s_cnt, 1);
                    if (p < GCAP) cand[p] = ((unsigned long long)bits << 32) | (unsigned)(0xFFFF - i);
                }
            }
        }
        __syncthreads();
        const int M2 = min(s_cnt, GCAP);
        for (int c = tid; c < M2; c += NTHR) {
            const unsigned long long kc = cand[c];
            int rank = 0;
            for (int j = 0; j < M2; ++j) rank += (cand[j] > kc) ? 1 : 0;
            if (rank < KSEL)
                outr[0xFFFF - (int)(kc & 0xFFFFu)] = __uint_as_float((unsigned)(kc >> 32));
        }
        __syncthreads();                                   // close row
    }
}

extern "C" void kernel_launch(void* const* d_in, const int* in_sizes, int n_in,
                              void* d_out, int out_size, void* d_ws, size_t ws_size,
                              hipStream_t stream) {
    const float* x = (const float*)d_in[0];
    float* out = (float*)d_out;
    const int rows = in_sizes[0] / COLS;
    hipLaunchKernelGGL(topk_fat_kernel, dim3(GRID), dim3(NTHR), 0, stream, x, out, rows);
}

// Round 7
// 223.659 us; speedup vs baseline: 2.0710x; 1.0656x over previous
//
#include <hip/hip_runtime.h>

#define COLS    32768
#define KSEL    32
#define GCAP    512       // per-row LDS candidate cap (expected ~203 at BAR=2.5, 21 sigma)
#define REF_CAP 256       // refined buffer after histogram prune (expected ~34)
#define NT      256
#define BAR     2.5f
#define TBLOCKS 2048      // 8 blocks/CU
#define NWRIT   256       // writer blocks (8 per 64-block group, XCD-spread)
#define NREAD   1792      // reader blocks

typedef float f32x4 __attribute__((ext_vector_type(4)));

// key = (float_bits << 32) | (0xFFFF - idx_in_row)
// positive float bits are monotonic in value; low 16 bits break ties so that
// larger key == (larger value, or equal value with smaller index) — matching
// jax.lax.top_k tie order. All keys distinct since idx distinct.
__device__ __forceinline__ unsigned long long mk_key(float v, int idx) {
    return ((unsigned long long)__float_as_uint(v) << 32) | (unsigned)(0xFFFF - idx);
}

// ---- K1: block-specialized. Writers: pure dense NT zero-fill of out (never
// read). Readers: pure row-read + select (never touch out); 32 result keys per
// row go to ws. Two pure streams run concurrently on disjoint CUs. ----
__global__ __launch_bounds__(NT, 8) void split_stream_kernel(
        const float* __restrict__ x, float* __restrict__ out,
        unsigned long long* __restrict__ wskeys, int rows, int nv4) {
    const int bid = blockIdx.x;
    const int group = bid >> 6, within = bid & 63;
    const int tid = threadIdx.x;

    if (within < 8) {
        // ---------- writer: grid-stride dense NT zero-fill ----------
        const int widx = group * 8 + within;            // [0, NWRIT)
        f32x4* __restrict__ o4 = (f32x4*)out;
        f32x4 z = 0;
        const int stride = NWRIT * NT;
#pragma unroll 4
        for (int g = widx * NT + tid; g < nv4; g += stride)
            __builtin_nontemporal_store(z, o4 + g);
        return;
    }

    // ---------- reader: per-row select, results to ws ----------
    __shared__ unsigned long long cand[GCAP];
    __shared__ unsigned long long refbuf[REF_CAP];
    __shared__ unsigned hist[256];
    __shared__ int s_cnt, s_bstar, s_rcnt, s_cum;

    const int ridx = group * 56 + (within - 8);         // [0, NREAD)

    for (int row = ridx; row < rows; row += NREAD) {
        const float* __restrict__ xr = x + (size_t)row * COLS;
        unsigned long long* __restrict__ wsrow = wskeys + (size_t)row * KSEL;
        const f32x4* __restrict__ xr4 = (const f32x4*)xr;

        if (tid == 0) { s_cnt = 0; s_rcnt = 0; }
        if (tid < KSEL) wsrow[tid] = 0;                 // sentinel (fallback rows)
        __syncthreads();                                // B1

        // pure read stream; rare (0.6%/lane) LDS candidate push
#pragma unroll 8
        for (int i = 0; i < COLS / 4 / NT; ++i) {       // 32 iters
            const int e = i * NT + tid;
            const f32x4 v = xr4[e];                     // cacheable: L3 serves ~half
            const float m = fmaxf(fmaxf(v.x, v.y), fmaxf(v.z, v.w));
            if (m > BAR) {
                const int bi = e * 4;
                if (v.x > BAR) { int p = atomicAdd(&s_cnt, 1); if (p < GCAP) cand[p] = mk_key(v.x, bi + 0); }
                if (v.y > BAR) { int p = atomicAdd(&s_cnt, 1); if (p < GCAP) cand[p] = mk_key(v.y, bi + 1); }
                if (v.z > BAR) { int p = atomicAdd(&s_cnt, 1); if (p < GCAP) cand[p] = mk_key(v.z, bi + 2); }
                if (v.w > BAR) { int p = atomicAdd(&s_cnt, 1); if (p < GCAP) cand[p] = mk_key(v.w, bi + 3); }
            }
        }
        __syncthreads();                                // B2
        const int N = s_cnt;

        if (N >= KSEL && N <= GCAP) {
            // histogram-prune candidates, then rank-select top-K
            hist[tid] = 0;
            __syncthreads();                            // B3
            for (int c = tid; c < N; c += NT) {
                unsigned bits = (unsigned)(cand[c] >> 32);
                unsigned b16 = (bits >> 16) - 0x4000u;  // bits >= 0x40200000 since v > 2.5
                if (b16 > 255u) b16 = 255u;             // saturate (keeps monotonicity)
                atomicAdd(&hist[b16], 1u);
            }
            __syncthreads();                            // B4
            // single-wave barrier-free suffix scan: lane owns bins [4l, 4l+3]
            if (tid < 64) {
                const int lane = tid;
                const unsigned h0 = hist[4 * lane + 0], h1 = hist[4 * lane + 1];
                const unsigned h2 = hist[4 * lane + 2], h3 = hist[4 * lane + 3];
                const unsigned s3 = h3, s2 = h2 + s3, s1 = h1 + s2, s0 = h0 + s1;
                unsigned acc = s0;
#pragma unroll
                for (int off = 1; off < 64; off <<= 1) {
                    unsigned o = __shfl_down(acc, off, 64);
                    if (lane + off < 64) acc += o;
                }
                const unsigned above = acc - s0;        // sum over lanes > lane
                const unsigned suf0 = above + s0, suf1 = above + s1;
                const unsigned suf2 = above + s2, suf3 = above + s3;
                unsigned nxt = __shfl_down(suf0, 1, 64);
                const unsigned suf4 = (lane == 63) ? 0u : nxt;
                if (suf0 >= KSEL && suf1 < KSEL) s_bstar = 4 * lane + 0;
                if (suf1 >= KSEL && suf2 < KSEL) s_bstar = 4 * lane + 1;
                if (suf2 >= KSEL && suf3 < KSEL) s_bstar = 4 * lane + 2;
                if (suf3 >= KSEL && suf4 < KSEL) s_bstar = 4 * lane + 3;
            }
            __syncthreads();                            // B5
            const int bstar = s_bstar;
            for (int c = tid; c < N; c += NT) {
                const unsigned long long kc = cand[c];
                unsigned bits = (unsigned)(kc >> 32);
                unsigned b16 = (bits >> 16) - 0x4000u;
                if (b16 > 255u) b16 = 255u;
                if ((int)b16 >= bstar) { int p = atomicAdd(&s_rcnt, 1); if (p < REF_CAP) refbuf[p] = kc; }
            }
            __syncthreads();                            // B6
            const int M = s_rcnt;
            if (M <= REF_CAP) {
                for (int c = tid; c < M; c += NT) {
                    const unsigned long long kc = refbuf[c];
                    int rank = 0;
                    for (int j = 0; j < M; ++j) rank += (refbuf[j] > kc) ? 1 : 0;
                    if (rank < KSEL) wsrow[rank] = kc;
                }
            } else {
                // refine overflow (mass ties) — exact rank over full candidate list
                for (int c = tid; c < N; c += NT) {
                    const unsigned long long kc = cand[c];
                    int rank = 0;
                    for (int j = 0; j < N; ++j) rank += (cand[j] > kc) ? 1 : 0;
                    if (rank < KSEL) wsrow[rank] = kc;
                }
            }
            __syncthreads();                            // B7: LDS safe for next row
            continue;
        }

        // exact fallback (N < K or overflow; never on N(0,1)): radix select,
        // re-reading the row; results to ws (sentinels already written).
        unsigned pref = 0, thr = 1;
        int need = KSEL, above = 0;
        for (int s = 24; s >= 0; s -= 8) {
            __syncthreads();
            hist[tid] = 0;
            __syncthreads();
            for (int i = tid; i < COLS; i += NT) {
                float v = xr[i];
                if (v > 0.f) {
                    unsigned bits = __float_as_uint(v);
                    if (s == 24 || (bits >> (s + 8)) == pref)
                        atomicAdd(&hist[(bits >> s) & 255u], 1u);
                }
            }
            __syncthreads();
            if (tid == 0) {
                int cum = 0, b = 255;
                for (; b >= 0; --b) { if (cum + (int)hist[b] >= need) break; cum += (int)hist[b]; }
                s_bstar = b; s_cum = cum;
            }
            __syncthreads();
            const int b = s_bstar, cum = s_cum;
            if (b < 0) { thr = 1; break; }   // fewer than K positives: take all positives
            above += cum;
            need -= cum;
            pref = (pref << 8) | (unsigned)b;
            thr = pref << s;
            const int total = above + (int)hist[b];
            if (total <= GCAP || s == 0) break;
        }
        __syncthreads();
        if (tid == 0) s_cnt = 0;
        __syncthreads();
        for (int i = tid; i < COLS; i += NT) {
            float v = xr[i];
            if (v > 0.f) {
                unsigned bits = __float_as_uint(v);
                if (bits >= thr) {
                    int p = atomicAdd(&s_cnt, 1);
                    if (p < GCAP) cand[p] = ((unsigned long long)bits << 32) | (unsigned)(0xFFFF - i);
                }
            }
        }
        __syncthreads();
        const int M2 = min(s_cnt, GCAP);
        for (int c = tid; c < M2; c += NT) {
            const unsigned long long kc = cand[c];
            int rank = 0;
            for (int j = 0; j < M2; ++j) rank += (cand[j] > kc) ? 1 : 0;
            if (rank < KSEL) wsrow[rank] = kc;
        }
        __syncthreads();                                // close row
    }
}

// ---- K2: tiny scatter of the selected positives into the zeroed out. ----
__global__ __launch_bounds__(64) void scatter_kernel(
        const unsigned long long* __restrict__ wskeys, float* __restrict__ out) {
    const int row = blockIdx.x;
    const int t = threadIdx.x;
    if (t < KSEL) {
        const unsigned long long key = wskeys[(size_t)row * KSEL + t];
        const float val = __uint_as_float((unsigned)(key >> 32));
        if (val > 0.f)
            out[(size_t)row * COLS + (0xFFFF - (int)(key & 0xFFFFu))] = val;
    }
}

// ---- fused single-kernel fallback (only if ws_size too small; R3-proven) ----
__global__ __launch_bounds__(NT, 8) void topk_fused_kernel(const float* __restrict__ x,
                                                           float* __restrict__ out) {
    __shared__ unsigned long long cand[GCAP];
    __shared__ unsigned long long refbuf[REF_CAP];
    __shared__ unsigned hist[256];
    __shared__ int s_cnt, s_bstar, s_rcnt, s_cum;

    const int tid = threadIdx.x;
    const size_t row = blockIdx.x;
    const float* __restrict__ xr = x + row * COLS;
    float* __restrict__ outr = out + row * COLS;

    if (tid == 0) { s_cnt = 0; s_rcnt = 0; }
    __syncthreads();

    const f32x4* __restrict__ xr4 = (const f32x4*)xr;
    f32x4* __restrict__ our4 = (f32x4*)outr;
#pragma unroll 4
    for (int i = 0; i < COLS / 4 / NT; ++i) {
        const int e = i * NT + tid;
        f32x4 v = __builtin_nontemporal_load(xr4 + e);
        f32x4 z = 0;
        __builtin_nontemporal_store(z, our4 + e);
        const float m = fmaxf(fmaxf(v.x, v.y), fmaxf(v.z, v.w));
        if (m > BAR) {
            const int bi = e * 4;
            if (v.x > BAR) { int p = atomicAdd(&s_cnt, 1); if (p < GCAP) cand[p] = mk_key(v.x, bi + 0); }
            if (v.y > BAR) { int p = atomicAdd(&s_cnt, 1); if (p < GCAP) cand[p] = mk_key(v.y, bi + 1); }
            if (v.z > BAR) { int p = atomicAdd(&s_cnt, 1); if (p < GCAP) cand[p] = mk_key(v.z, bi + 2); }
            if (v.w > BAR) { int p = atomicAdd(&s_cnt, 1); if (p < GCAP) cand[p] = mk_key(v.w, bi + 3); }
        }
    }
    __syncthreads();
    const int N = s_cnt;

    if (N >= KSEL && N <= GCAP) {
        hist[tid] = 0;
        __syncthreads();
        for (int c = tid; c < N; c += NT) {
            unsigned bits = (unsigned)(cand[c] >> 32);
            unsigned b16 = (bits >> 16) - 0x4000u;
            if (b16 > 255u) b16 = 255u;
            atomicAdd(&hist[b16], 1u);
        }
        __syncthreads();
        if (tid < 64) {
            const int lane = tid;
            const unsigned h0 = hist[4 * lane + 0], h1 = hist[4 * lane + 1];
            const unsigned h2 = hist[4 * lane + 2], h3 = hist[4 * lane + 3];
            const unsigned s3 = h3, s2 = h2 + s3, s1 = h1 + s2, s0 = h0 + s1;
            unsigned acc = s0;
#pragma unroll
            for (int off = 1; off < 64; off <<= 1) {
                unsigned o = __shfl_down(acc, off, 64);
                if (lane + off < 64) acc += o;
            }
            const unsigned above = acc - s0;
            const unsigned suf0 = above + s0, suf1 = above + s1;
            const unsigned suf2 = above + s2, suf3 = above + s3;
            unsigned nxt = __shfl_down(suf0, 1, 64);
            const unsigned suf4 = (lane == 63) ? 0u : nxt;
            if (suf0 >= KSEL && suf1 < KSEL) s_bstar = 4 * lane + 0;
            if (suf1 >= KSEL && suf2 < KSEL) s_bstar = 4 * lane + 1;
            if (suf2 >= KSEL && suf3 < KSEL) s_bstar = 4 * lane + 2;
            if (suf3 >= KSEL && suf4 < KSEL) s_bstar = 4 * lane + 3;
        }
        __syncthreads();
        const int bstar = s_bstar;
        for (int c = tid; c < N; c += NT) {
            const unsigned long long kc = cand[c];
            unsigned bits = (unsigned)(kc >> 32);
            unsigned b16 = (bits >> 16) - 0x4000u;
            if (b16 > 255u) b16 = 255u;
            if ((int)b16 >= bstar) { int p = atomicAdd(&s_rcnt, 1); if (p < REF_CAP) refbuf[p] = kc; }
        }
        __syncthreads();
        const int M = s_rcnt;
        if (M <= REF_CAP) {
            for (int c = tid; c < M; c += NT) {
                const unsigned long long kc = refbuf[c];
                int rank = 0;
                for (int j = 0; j < M; ++j) rank += (refbuf[j] > kc) ? 1 : 0;
                if (rank < KSEL)
                    outr[0xFFFF - (int)(kc & 0xFFFFu)] = __uint_as_float((unsigned)(kc >> 32));
            }
        } else {
            for (int c = tid; c < N; c += NT) {
                const unsigned long long kc = cand[c];
                int rank = 0;
                for (int j = 0; j < N; ++j) rank += (cand[j] > kc) ? 1 : 0;
                if (rank < KSEL)
                    outr[0xFFFF - (int)(kc & 0xFFFFu)] = __uint_as_float((unsigned)(kc >> 32));
            }
        }
        return;
    }

    unsigned pref = 0, thr = 1;
    int need = KSEL, above = 0;
    for (int s = 24; s >= 0; s -= 8) {
        __syncthreads();
        hist[tid] = 0;
        __syncthreads();
        for (int i = tid; i < COLS; i += NT) {
            float v = xr[i];
            if (v > 0.f) {
                unsigned bits = __float_as_uint(v);
                if (s == 24 || (bits >> (s + 8)) == pref)
                    atomicAdd(&hist[(bits >> s) & 255u], 1u);
            }
        }
        __syncthreads();
        if (tid == 0) {
            int cum = 0, b = 255;
            for (; b >= 0; --b) { if (cum + (int)hist[b] >= need) break; cum += (int)hist[b]; }
            s_bstar = b; s_cum = cum;
        }
        __syncthreads();
        const int b = s_bstar, cum = s_cum;
        if (b < 0) { thr = 1; break; }
        above += cum;
        need -= cum;
        pref = (pref << 8) | (unsigned)b;
        thr = pref << s;
        const int total = above + (int)hist[b];
        if (total <= GCAP || s == 0) break;
    }
    __syncthreads();
    if (tid == 0) s_cnt = 0;
    __syncthreads();
    for (int i = tid; i < COLS; i += NT) {
        float v = xr[i];
        if (v > 0.f) {
            unsigned bits = __float_as_uint(v);
            if (bits >= thr) {
                int p = atomicAdd(&s_cnt, 1);
                if (p < GCAP) cand[p] = ((unsigned long long)bits << 32) | (unsigned)(0xFFFF - i);
            }
        }
    }
    __syncthreads();
    const int M2 = min(s_cnt, GCAP);
    for (int c = tid; c < M2; c += NT) {
        const unsigned long long kc = cand[c];
        int rank = 0;
        for (int j = 0; j < M2; ++j) rank += (cand[j] > kc) ? 1 : 0;
        if (rank < KSEL)
            outr[0xFFFF - (int)(kc & 0xFFFFu)] = __uint_as_float((unsigned)(kc >> 32));
    }
}

extern "C" void kernel_launch(void* const* d_in, const int* in_sizes, int n_in,
                              void* d_out, int out_size, void* d_ws, size_t ws_size,
                              hipStream_t stream) {
    const float* x = (const float*)d_in[0];
    float* out = (float*)d_out;
    const int rows = in_sizes[0] / COLS;
    const int nv4 = in_sizes[0] / 4;
    const size_t need = (size_t)rows * KSEL * sizeof(unsigned long long);   // 1 MB

    if (ws_size >= need) {
        unsigned long long* wskeys = (unsigned long long*)d_ws;
        hipLaunchKernelGGL(split_stream_kernel, dim3(TBLOCKS), dim3(NT), 0, stream,
                           x, out, wskeys, rows, nv4);
        hipLaunchKernelGGL(scatter_kernel, dim3(rows), dim3(64), 0, stream,
                           wskeys, out);
    } else {
        hipLaunchKernelGGL(topk_fused_kernel, dim3(rows), dim3(NT), 0, stream, x, out);
    }
}